// Round 1
// baseline (6865.192 us; speedup 1.0000x reference)
//
#include <hip/hip_runtime.h>
#include <hip/hip_bf16.h>
#include <math.h>

#define C 128
#define NN 50000
#define EE 600000
#define GG 256
#define PI_F 3.14159265358979323846f
#define EPS_BN 1e-5f

// ---------------- CSR build ----------------
__global__ void k_count(const int* __restrict__ dst, int* __restrict__ deg) {
    int e = blockIdx.x * blockDim.x + threadIdx.x;
    if (e < EE) atomicAdd(&deg[dst[e]], 1);
}

__global__ void k_scan(const int* __restrict__ deg, int* __restrict__ row_ptr) {
    __shared__ int s[1024];
    int t = threadIdx.x;
    const int CH = (NN + 1023) / 1024;
    int base = t * CH;
    int loc = 0;
    for (int i = 0; i < CH; i++) { int idx = base + i; if (idx < NN) loc += deg[idx]; }
    s[t] = loc; __syncthreads();
    for (int off = 1; off < 1024; off <<= 1) {
        int v = (t >= off) ? s[t - off] : 0;
        __syncthreads();
        s[t] += v;
        __syncthreads();
    }
    int run = (t == 0) ? 0 : s[t - 1];
    for (int i = 0; i < CH; i++) {
        int idx = base + i;
        if (idx < NN) { row_ptr[idx] = run; run += deg[idx]; }
    }
    if (t == 0) row_ptr[NN] = s[1023];
}

__global__ void k_fill(const int* __restrict__ dst, const int* __restrict__ row_ptr,
                       int* __restrict__ fill, int* __restrict__ eid) {
    int e = blockIdx.x * blockDim.x + threadIdx.x;
    if (e < EE) {
        int d = dst[e];
        int pos = atomicAdd(&fill[d], 1);
        eid[row_ptr[d] + pos] = e;
    }
}

// ---------------- GEMM: out[M x C] = in[M x C] @ W[C x C] + b ----------------
// W staged in LDS (64KB). 256 threads = 2 row-groups x 128 output cols.
template<bool TANH, bool OUT_BF16>
__launch_bounds__(256)
__global__ void k_gemm(const float* __restrict__ in, const float* __restrict__ W,
                       const float* __restrict__ bias, void* __restrict__ outv, int M,
                       int rowsPerBlock) {
    __shared__ float sW[C * C];
    for (int i = threadIdx.x; i < C * C; i += 256) sW[i] = W[i];
    __syncthreads();
    int j  = threadIdx.x & (C - 1);
    int rg = threadIdx.x >> 7;
    float b = bias ? bias[j] : 0.f;
    int r0 = blockIdx.x * rowsPerBlock;
    int r1 = min(r0 + rowsPerBlock, M);
    for (int row = r0 + rg; row < r1; row += 2) {
        const float* rp = in + (size_t)row * C;
        float acc = b;
        #pragma unroll 8
        for (int k = 0; k < C; ++k) acc = fmaf(rp[k], sW[k * C + j], acc);
        if (TANH) acc = tanhf(acc);
        if (OUT_BF16) ((__hip_bfloat16*)outv)[(size_t)row * C + j] = __float2bfloat16(acc);
        else          ((float*)outv)[(size_t)row * C + j] = acc;
    }
}

// ---------------- loopW[n] = (sum of eW rows of incoming edges) / max(deg,1) ----------------
__global__ void k_loopw(const __hip_bfloat16* __restrict__ eW, const int* __restrict__ row_ptr,
                        const int* __restrict__ eid, const int* __restrict__ deg,
                        float* __restrict__ loopW) {
    int n = blockIdx.x; int c = threadIdx.x;
    int s = row_ptr[n], e = row_ptr[n + 1];
    float acc = 0.f;
    for (int i = s; i < e; i++) acc += __bfloat162float(eW[(size_t)eid[i] * C + c]);
    loopW[(size_t)n * C + c] = acc / fmaxf((float)deg[n], 1.f);
}

// ---------------- per-edge attention logits (one wave per edge) ----------------
__global__ void k_apass(const float* __restrict__ xl, const float* __restrict__ xr,
                        const __hip_bfloat16* __restrict__ eW, const float* __restrict__ loopW,
                        const int* __restrict__ src, const int* __restrict__ dst,
                        const float* __restrict__ att, float* __restrict__ a) {
    int gid = blockIdx.x * blockDim.x + threadIdx.x;
    int w = gid >> 6, lane = gid & 63;
    if (w >= EE + NN) return;
    float p = 0.f;
    if (w < EE) {
        int s = src[w], d = dst[w];
        #pragma unroll
        for (int c = lane; c < C; c += 64) {
            float m = xl[(size_t)s * C + c] + xr[(size_t)d * C + c]
                    + __bfloat162float(eW[(size_t)w * C + c]);
            m = (m >= 0.f) ? m : 0.2f * m;
            p += m * att[c];
        }
    } else {
        int i = w - EE;
        #pragma unroll
        for (int c = lane; c < C; c += 64) {
            float m = xl[(size_t)i * C + c] + xr[(size_t)i * C + c] + loopW[(size_t)i * C + c];
            m = (m >= 0.f) ? m : 0.2f * m;
            p += m * att[c];
        }
    }
    #pragma unroll
    for (int off = 32; off; off >>= 1) p += __shfl_down(p, off);
    if (lane == 0) a[w] = p;
}

// ---------------- scatter softmax over incoming edges (thread per node) ----------------
__global__ void k_softmax(const int* __restrict__ row_ptr, const int* __restrict__ eid,
                          const float* __restrict__ a, float* __restrict__ alpha) {
    int n = blockIdx.x * blockDim.x + threadIdx.x;
    if (n >= NN) return;
    int s = row_ptr[n], e = row_ptr[n + 1];
    float self = a[EE + n];
    float amax = self;
    for (int i = s; i < e; i++) amax = fmaxf(amax, a[eid[i]]);
    float den = 0.f;
    for (int i = s; i < e; i++) { float ex = expf(a[eid[i]] - amax); alpha[eid[i]] = ex; den += ex; }
    float exs = expf(self - amax); den += exs;
    float inv = 1.f / den;
    for (int i = s; i < e; i++) alpha[eid[i]] *= inv;
    alpha[EE + n] = exs * inv;
}

// ---------------- aggregation: out[n] = sum alpha_e * xl[src_e] + alpha_self*xl[n] + bo ----------------
__global__ void k_agg(const float* __restrict__ xl, const float* __restrict__ alpha,
                      const int* __restrict__ row_ptr, const int* __restrict__ eid,
                      const int* __restrict__ src, const float* __restrict__ bo,
                      float* __restrict__ out) {
    int n = blockIdx.x; int c = threadIdx.x;
    float acc = alpha[EE + n] * xl[(size_t)n * C + c];
    int s = row_ptr[n], e = row_ptr[n + 1];
    for (int i = s; i < e; i++) {
        int ed = eid[i];
        acc += alpha[ed] * xl[(size_t)src[ed] * C + c];
    }
    out[(size_t)n * C + c] = acc + bo[c];
}

// ---------------- batchnorm ----------------
__global__ void k_bnstats(const float* __restrict__ v, float* __restrict__ sums) {
    int c = threadIdx.x;
    float s1 = 0.f, s2 = 0.f;
    for (int n = blockIdx.x; n < NN; n += gridDim.x) {
        float x = v[(size_t)n * C + c]; s1 += x; s2 += x * x;
    }
    atomicAdd(&sums[c], s1); atomicAdd(&sums[C + c], s2);
}

__global__ void k_bnapply(const float* __restrict__ v, const float* __restrict__ sums,
                          const float* __restrict__ g, const float* __restrict__ b,
                          float* __restrict__ h) {
    int idx = blockIdx.x * blockDim.x + threadIdx.x;
    if (idx >= NN * C) return;
    int c = idx & (C - 1);
    float mu  = sums[c] * (1.f / NN);
    float var = sums[C + c] * (1.f / NN) - mu * mu;
    float r = rsqrtf(var + EPS_BN);
    h[idx] = tanhf((v[idx] - mu) * r * g[c] + b[c]);
}

// ---------------- graph segment bounds ----------------
__global__ void k_bounds(const int* __restrict__ batch, int* __restrict__ gs, int* __restrict__ ge) {
    int n = blockIdx.x * blockDim.x + threadIdx.x;
    if (n >= NN) return;
    int b = batch[n];
    if (n == 0 || batch[n - 1] != b) gs[b] = n;
    if (n == NN - 1 || batch[n + 1] != b) ge[b] = n + 1;
}

// ---------------- attention pooling (block per graph) ----------------
__global__ void k_pool(const float* __restrict__ gate, const float* __restrict__ h,
                       const int* __restrict__ gs, const int* __restrict__ ge,
                       float* __restrict__ pooled) {
    int g = blockIdx.x; int c = threadIdx.x;
    int s = gs[g], e = ge[g];
    float m = -1e30f;
    for (int n = s; n < e; n++) m = fmaxf(m, gate[(size_t)n * C + c]);
    float den = 0.f, acc = 0.f;
    for (int n = s; n < e; n++) {
        float w = expf(gate[(size_t)n * C + c] - m);
        den += w; acc += w * h[(size_t)n * C + c];
    }
    pooled[g * C + c] = (e > s) ? acc / den : 0.f;
}

// ---------------- final linear + tanh + split/scale ----------------
__global__ void k_final(const float* __restrict__ pooled, const float* __restrict__ Wf,
                        const float* __restrict__ bf, float* __restrict__ out) {
    __shared__ float row[C];
    int g = blockIdx.x; int j = threadIdx.x;
    row[j] = pooled[g * C + j];
    __syncthreads();
    float acc = bf[j];
    #pragma unroll 8
    for (int k = 0; k < C; k++) acc = fmaf(row[k], Wf[k * C + j], acc);
    float o = tanhf(acc);
    if (j < C / 2) out[g * (C / 2) + j] = o * PI_F;
    else out[GG * (C / 2) + g * (C / 2) + (j - C / 2)] = (o + 1.f) * PI_F;
}

extern "C" void kernel_launch(void* const* d_in, const int* in_sizes, int n_in,
                              void* d_out, int out_size, void* d_ws, size_t ws_size,
                              hipStream_t stream) {
    const float* x   = (const float*)d_in[0];
    const int*   ei  = (const int*)d_in[1];
    const float* ea  = (const float*)d_in[2];
    const int* batch = (const int*)d_in[3];
    const float *Wl1 = (const float*)d_in[4],  *bl1 = (const float*)d_in[5];
    const float *Wr1 = (const float*)d_in[6],  *br1 = (const float*)d_in[7];
    const float *We1 = (const float*)d_in[8],  *att1 = (const float*)d_in[9], *bo1 = (const float*)d_in[10];
    const float *Wl2 = (const float*)d_in[11], *bl2 = (const float*)d_in[12];
    const float *Wr2 = (const float*)d_in[13], *br2 = (const float*)d_in[14];
    const float *We2 = (const float*)d_in[15], *att2 = (const float*)d_in[16], *bo2 = (const float*)d_in[17];
    const float *g1  = (const float*)d_in[18], *be1 = (const float*)d_in[19];
    const float *g2  = (const float*)d_in[20], *be2 = (const float*)d_in[21];
    const float *Ag1 = (const float*)d_in[22], *bg1 = (const float*)d_in[23];
    const float *Ag2 = (const float*)d_in[24], *bg2 = (const float*)d_in[25];
    const float *Wf  = (const float*)d_in[26], *bf  = (const float*)d_in[27];
    const int* src = ei; const int* dst = ei + EE;

    char* wsb = (char*)d_ws;
    size_t off = 0;
    auto alloc = [&](size_t bytes) -> char* {
        char* p = wsb + off; off += (bytes + 255) & ~(size_t)255; return p;
    };
    float* B0 = (float*)alloc((size_t)NN * C * 4);
    float* B1 = (float*)alloc((size_t)NN * C * 4);
    float* B2 = (float*)alloc((size_t)NN * C * 4);
    float* B3 = (float*)alloc((size_t)NN * C * 4);
    __hip_bfloat16* eW = (__hip_bfloat16*)alloc((size_t)EE * C * 2);
    float* a     = (float*)alloc((size_t)(EE + NN) * 4);
    float* alpha = (float*)alloc((size_t)(EE + NN) * 4);
    int* deg     = (int*)alloc((size_t)NN * 4);
    int* row_ptr = (int*)alloc((size_t)(NN + 1) * 4);
    int* fill    = (int*)alloc((size_t)NN * 4);
    int* eid     = (int*)alloc((size_t)EE * 4);
    float* sums  = (float*)alloc(2 * C * 4);
    int* gs      = (int*)alloc(GG * 4);
    int* ge      = (int*)alloc(GG * 4);
    float* pooled= (float*)alloc(GG * C * 4);

    hipMemsetAsync(deg,  0, (size_t)NN * 4, stream);
    hipMemsetAsync(fill, 0, (size_t)NN * 4, stream);
    hipMemsetAsync(gs,   0, GG * 4, stream);
    hipMemsetAsync(ge,   0, GG * 4, stream);

    k_count<<<(EE + 255) / 256, 256, 0, stream>>>(dst, deg);
    k_scan<<<1, 1024, 0, stream>>>(deg, row_ptr);
    k_fill<<<(EE + 255) / 256, 256, 0, stream>>>(dst, row_ptr, fill, eid);

    const int RPB = 64;
    int gN = (NN + RPB - 1) / RPB, gE = (EE + RPB - 1) / RPB;
    long long tw = (long long)(EE + NN) * 64;
    int apassBlocks = (int)((tw + 255) / 256);

    // ---- layer 1 ----
    k_gemm<false, false><<<gN, 256, 0, stream>>>(x, Wl1, bl1, B0, NN, RPB);
    k_gemm<false, false><<<gN, 256, 0, stream>>>(x, Wr1, br1, B1, NN, RPB);
    k_gemm<false, true ><<<gE, 256, 0, stream>>>(ea, We1, nullptr, eW, EE, RPB);
    k_loopw<<<NN, C, 0, stream>>>(eW, row_ptr, eid, deg, B2);
    k_apass<<<apassBlocks, 256, 0, stream>>>(B0, B1, eW, B2, src, dst, att1, a);
    k_softmax<<<(NN + 255) / 256, 256, 0, stream>>>(row_ptr, eid, a, alpha);
    k_agg<<<NN, C, 0, stream>>>(B0, alpha, row_ptr, eid, src, bo1, B3);
    hipMemsetAsync(sums, 0, 2 * C * 4, stream);
    k_bnstats<<<256, C, 0, stream>>>(B3, sums);
    k_bnapply<<<(NN * C + 255) / 256, 256, 0, stream>>>(B3, sums, g1, be1, B0); // h -> B0

    // ---- layer 2 ----
    k_gemm<false, false><<<gN, 256, 0, stream>>>(B0, Wl2, bl2, B1, NN, RPB);
    k_gemm<false, false><<<gN, 256, 0, stream>>>(B0, Wr2, br2, B2, NN, RPB);
    k_gemm<false, true ><<<gE, 256, 0, stream>>>(ea, We2, nullptr, eW, EE, RPB);
    k_loopw<<<NN, C, 0, stream>>>(eW, row_ptr, eid, deg, B3);
    k_apass<<<apassBlocks, 256, 0, stream>>>(B1, B2, eW, B3, src, dst, att2, a);
    k_softmax<<<(NN + 255) / 256, 256, 0, stream>>>(row_ptr, eid, a, alpha);
    k_agg<<<NN, C, 0, stream>>>(B1, alpha, row_ptr, eid, src, bo2, B0);
    hipMemsetAsync(sums, 0, 2 * C * 4, stream);
    k_bnstats<<<256, C, 0, stream>>>(B0, sums);
    k_bnapply<<<(NN * C + 255) / 256, 256, 0, stream>>>(B0, sums, g2, be2, B3); // h2 -> B3

    // ---- pooling + head ----
    k_gemm<true,  false><<<gN, 256, 0, stream>>>(B3, Ag1, bg1, B1, NN, RPB);
    k_gemm<false, false><<<gN, 256, 0, stream>>>(B1, Ag2, bg2, B2, NN, RPB);
    k_bounds<<<(NN + 255) / 256, 256, 0, stream>>>(batch, gs, ge);
    k_pool<<<GG, C, 0, stream>>>(B2, B3, gs, ge, pooled);
    k_final<<<GG, C, 0, stream>>>(pooled, Wf, bf, (float*)d_out);
}

// Round 2
// 2022.198 us; speedup vs baseline: 3.3949x; 3.3949x over previous
//
#include <hip/hip_runtime.h>
#include <hip/hip_bf16.h>
#include <math.h>

#define C 128
#define NN 50000
#define EE 600000
#define GG 256
#define PI_F 3.14159265358979323846f
#define EPS_BN 1e-5f

typedef __attribute__((ext_vector_type(8)))  short  short8;
typedef __attribute__((ext_vector_type(16))) float  floatx16;
typedef __attribute__((ext_vector_type(4)))  float  float4v;

static __device__ __forceinline__ short f2bs(float x) {
    union { float f; unsigned u; } v; v.f = x;
    unsigned r = v.u + 0x7FFF + ((v.u >> 16) & 1);
    return (short)(r >> 16);
}

// ---------------- CSR build ----------------
__global__ void k_count(const int* __restrict__ dst, int* __restrict__ deg) {
    int e = blockIdx.x * blockDim.x + threadIdx.x;
    if (e < EE) atomicAdd(&deg[dst[e]], 1);
}

__global__ void k_scan(const int* __restrict__ deg, int* __restrict__ row_ptr) {
    __shared__ int s[1024];
    int t = threadIdx.x;
    const int CH = (NN + 1023) / 1024;
    int base = t * CH;
    int loc = 0;
    for (int i = 0; i < CH; i++) { int idx = base + i; if (idx < NN) loc += deg[idx]; }
    s[t] = loc; __syncthreads();
    for (int off = 1; off < 1024; off <<= 1) {
        int v = (t >= off) ? s[t - off] : 0;
        __syncthreads();
        s[t] += v;
        __syncthreads();
    }
    int run = (t == 0) ? 0 : s[t - 1];
    for (int i = 0; i < CH; i++) {
        int idx = base + i;
        if (idx < NN) { row_ptr[idx] = run; run += deg[idx]; }
    }
    if (t == 0) row_ptr[NN] = s[1023];
}

__global__ void k_fill(const int* __restrict__ dst, const int* __restrict__ row_ptr,
                       int* __restrict__ fill, int* __restrict__ eid) {
    int e = blockIdx.x * blockDim.x + threadIdx.x;
    if (e < EE) {
        int d = dst[e];
        int pos = atomicAdd(&fill[d], 1);
        eid[row_ptr[d] + pos] = e;
    }
}

// ---------------- MFMA GEMM: out[M x C] = in[M x C] @ W[C x C] + b ----------------
// 256 thr = 4 waves; block computes 128 rows x 128 cols via 32x32x16 bf16 MFMA.
// W transposed into LDS bf16, row stride 136 shorts (272 B) -> even bank spread.
template<bool TANH, bool OUT_BF16>
__launch_bounds__(256)
__global__ void k_gemm_mfma(const float* __restrict__ in, const float* __restrict__ W,
                            const float* __restrict__ bias, void* __restrict__ outv, int M) {
    __shared__ short sWT[C * 136];
    for (int i = threadIdx.x; i < C * C; i += 256) {
        int k = i >> 7, n = i & (C - 1);
        sWT[n * 136 + k] = f2bs(W[i]);
    }
    __syncthreads();

    int lane = threadIdx.x & 63;
    int wave = threadIdx.x >> 6;
    int m    = lane & 31;
    int half = lane >> 5;
    int row0 = blockIdx.x * 128 + wave * 32;
    int rowA = row0 + m;
    int rowC = (rowA < M) ? rowA : (M - 1);      // clamp for safe loads
    const float* rp = in + (size_t)rowC * C;

    floatx16 acc[4];
    #pragma unroll
    for (int t = 0; t < 4; ++t)
        #pragma unroll
        for (int r = 0; r < 16; ++r) acc[t][r] = 0.f;

    #pragma unroll
    for (int s = 0; s < 8; ++s) {
        int k0 = s * 16 + half * 8;
        float4v a0 = *(const float4v*)(rp + k0);
        float4v a1 = *(const float4v*)(rp + k0 + 4);
        short8 af;
        af[0] = f2bs(a0.x); af[1] = f2bs(a0.y); af[2] = f2bs(a0.z); af[3] = f2bs(a0.w);
        af[4] = f2bs(a1.x); af[5] = f2bs(a1.y); af[6] = f2bs(a1.z); af[7] = f2bs(a1.w);
        #pragma unroll
        for (int t = 0; t < 4; ++t) {
            short8 bfr = *(const short8*)(&sWT[(t * 32 + m) * 136 + k0]);
            acc[t] = __builtin_amdgcn_mfma_f32_32x32x16_bf16(af, bfr, acc[t], 0, 0, 0);
        }
    }

    #pragma unroll
    for (int t = 0; t < 4; ++t) {
        int n = t * 32 + m;
        float b = bias ? bias[n] : 0.f;
        #pragma unroll
        for (int r = 0; r < 16; ++r) {
            int rl  = (r & 3) + 8 * (r >> 2) + 4 * half;
            int row = row0 + rl;
            if (row < M) {
                float v = acc[t][r] + b;
                if (TANH) v = tanhf(v);
                if (OUT_BF16) ((__hip_bfloat16*)outv)[(size_t)row * C + n] = __float2bfloat16(v);
                else          ((float*)outv)[(size_t)row * C + n] = v;
            }
        }
    }
}

// ---------------- loopW[n] = (sum of eW rows of incoming edges) / max(deg,1) ----------------
__global__ void k_loopw(const __hip_bfloat16* __restrict__ eW, const int* __restrict__ row_ptr,
                        const int* __restrict__ eid, const int* __restrict__ deg,
                        float* __restrict__ loopW) {
    int n = blockIdx.x; int c = threadIdx.x;
    int s = row_ptr[n], e = row_ptr[n + 1];
    float acc = 0.f;
    for (int i = s; i < e; i++) acc += __bfloat162float(eW[(size_t)eid[i] * C + c]);
    loopW[(size_t)n * C + c] = acc / fmaxf((float)deg[n], 1.f);
}

// ---------------- per-edge attention logits (one wave per edge) ----------------
__global__ void k_apass(const float* __restrict__ xl, const float* __restrict__ xr,
                        const __hip_bfloat16* __restrict__ eW, const float* __restrict__ loopW,
                        const int* __restrict__ src, const int* __restrict__ dst,
                        const float* __restrict__ att, float* __restrict__ a) {
    int gid = blockIdx.x * blockDim.x + threadIdx.x;
    int w = gid >> 6, lane = gid & 63;
    if (w >= EE + NN) return;
    float p = 0.f;
    if (w < EE) {
        int s = src[w], d = dst[w];
        #pragma unroll
        for (int c = lane; c < C; c += 64) {
            float m = xl[(size_t)s * C + c] + xr[(size_t)d * C + c]
                    + __bfloat162float(eW[(size_t)w * C + c]);
            m = (m >= 0.f) ? m : 0.2f * m;
            p += m * att[c];
        }
    } else {
        int i = w - EE;
        #pragma unroll
        for (int c = lane; c < C; c += 64) {
            float m = xl[(size_t)i * C + c] + xr[(size_t)i * C + c] + loopW[(size_t)i * C + c];
            m = (m >= 0.f) ? m : 0.2f * m;
            p += m * att[c];
        }
    }
    #pragma unroll
    for (int off = 32; off; off >>= 1) p += __shfl_down(p, off);
    if (lane == 0) a[w] = p;
}

// ---------------- scatter softmax over incoming edges (thread per node) ----------------
__global__ void k_softmax(const int* __restrict__ row_ptr, const int* __restrict__ eid,
                          const float* __restrict__ a, float* __restrict__ alpha) {
    int n = blockIdx.x * blockDim.x + threadIdx.x;
    if (n >= NN) return;
    int s = row_ptr[n], e = row_ptr[n + 1];
    float self = a[EE + n];
    float amax = self;
    for (int i = s; i < e; i++) amax = fmaxf(amax, a[eid[i]]);
    float den = 0.f;
    for (int i = s; i < e; i++) { float ex = expf(a[eid[i]] - amax); alpha[eid[i]] = ex; den += ex; }
    float exs = expf(self - amax); den += exs;
    float inv = 1.f / den;
    for (int i = s; i < e; i++) alpha[eid[i]] *= inv;
    alpha[EE + n] = exs * inv;
}

// ---------------- aggregation ----------------
__global__ void k_agg(const float* __restrict__ xl, const float* __restrict__ alpha,
                      const int* __restrict__ row_ptr, const int* __restrict__ eid,
                      const int* __restrict__ src, const float* __restrict__ bo,
                      float* __restrict__ out) {
    int n = blockIdx.x; int c = threadIdx.x;
    float acc = alpha[EE + n] * xl[(size_t)n * C + c];
    int s = row_ptr[n], e = row_ptr[n + 1];
    for (int i = s; i < e; i++) {
        int ed = eid[i];
        acc += alpha[ed] * xl[(size_t)src[ed] * C + c];
    }
    out[(size_t)n * C + c] = acc + bo[c];
}

// ---------------- batchnorm ----------------
__global__ void k_bnstats(const float* __restrict__ v, float* __restrict__ sums) {
    int c = threadIdx.x;
    float s1 = 0.f, s2 = 0.f;
    for (int n = blockIdx.x; n < NN; n += gridDim.x) {
        float x = v[(size_t)n * C + c]; s1 += x; s2 += x * x;
    }
    atomicAdd(&sums[c], s1); atomicAdd(&sums[C + c], s2);
}

__global__ void k_bnapply(const float* __restrict__ v, const float* __restrict__ sums,
                          const float* __restrict__ g, const float* __restrict__ b,
                          float* __restrict__ h) {
    int idx = blockIdx.x * blockDim.x + threadIdx.x;
    if (idx >= NN * C) return;
    int c = idx & (C - 1);
    float mu  = sums[c] * (1.f / NN);
    float var = sums[C + c] * (1.f / NN) - mu * mu;
    float r = rsqrtf(var + EPS_BN);
    h[idx] = tanhf((v[idx] - mu) * r * g[c] + b[c]);
}

// ---------------- graph segment bounds ----------------
__global__ void k_bounds(const int* __restrict__ batch, int* __restrict__ gs, int* __restrict__ ge) {
    int n = blockIdx.x * blockDim.x + threadIdx.x;
    if (n >= NN) return;
    int b = batch[n];
    if (n == 0 || batch[n - 1] != b) gs[b] = n;
    if (n == NN - 1 || batch[n + 1] != b) ge[b] = n + 1;
}

// ---------------- attention pooling (block per graph) ----------------
__global__ void k_pool(const float* __restrict__ gate, const float* __restrict__ h,
                       const int* __restrict__ gs, const int* __restrict__ ge,
                       float* __restrict__ pooled) {
    int g = blockIdx.x; int c = threadIdx.x;
    int s = gs[g], e = ge[g];
    float m = -1e30f;
    for (int n = s; n < e; n++) m = fmaxf(m, gate[(size_t)n * C + c]);
    float den = 0.f, acc = 0.f;
    for (int n = s; n < e; n++) {
        float w = expf(gate[(size_t)n * C + c] - m);
        den += w; acc += w * h[(size_t)n * C + c];
    }
    pooled[g * C + c] = (e > s) ? acc / den : 0.f;
}

// ---------------- final linear + tanh + split/scale ----------------
__global__ void k_final(const float* __restrict__ pooled, const float* __restrict__ Wf,
                        const float* __restrict__ bf, float* __restrict__ out) {
    __shared__ float row[C];
    int g = blockIdx.x; int j = threadIdx.x;
    row[j] = pooled[g * C + j];
    __syncthreads();
    float acc = bf[j];
    #pragma unroll 8
    for (int k = 0; k < C; k++) acc = fmaf(row[k], Wf[k * C + j], acc);
    float o = tanhf(acc);
    if (j < C / 2) out[g * (C / 2) + j] = o * PI_F;
    else out[GG * (C / 2) + g * (C / 2) + (j - C / 2)] = (o + 1.f) * PI_F;
}

extern "C" void kernel_launch(void* const* d_in, const int* in_sizes, int n_in,
                              void* d_out, int out_size, void* d_ws, size_t ws_size,
                              hipStream_t stream) {
    const float* x   = (const float*)d_in[0];
    const int*   ei  = (const int*)d_in[1];
    const float* ea  = (const float*)d_in[2];
    const int* batch = (const int*)d_in[3];
    const float *Wl1 = (const float*)d_in[4],  *bl1 = (const float*)d_in[5];
    const float *Wr1 = (const float*)d_in[6],  *br1 = (const float*)d_in[7];
    const float *We1 = (const float*)d_in[8],  *att1 = (const float*)d_in[9], *bo1 = (const float*)d_in[10];
    const float *Wl2 = (const float*)d_in[11], *bl2 = (const float*)d_in[12];
    const float *Wr2 = (const float*)d_in[13], *br2 = (const float*)d_in[14];
    const float *We2 = (const float*)d_in[15], *att2 = (const float*)d_in[16], *bo2 = (const float*)d_in[17];
    const float *g1  = (const float*)d_in[18], *be1 = (const float*)d_in[19];
    const float *g2  = (const float*)d_in[20], *be2 = (const float*)d_in[21];
    const float *Ag1 = (const float*)d_in[22], *bg1 = (const float*)d_in[23];
    const float *Ag2 = (const float*)d_in[24], *bg2 = (const float*)d_in[25];
    const float *Wf  = (const float*)d_in[26], *bf  = (const float*)d_in[27];
    const int* src = ei; const int* dst = ei + EE;

    char* wsb = (char*)d_ws;
    size_t off = 0;
    auto alloc = [&](size_t bytes) -> char* {
        char* p = wsb + off; off += (bytes + 255) & ~(size_t)255; return p;
    };
    float* B0 = (float*)alloc((size_t)NN * C * 4);
    float* B1 = (float*)alloc((size_t)NN * C * 4);
    float* B2 = (float*)alloc((size_t)NN * C * 4);
    float* B3 = (float*)alloc((size_t)NN * C * 4);
    __hip_bfloat16* eW = (__hip_bfloat16*)alloc((size_t)EE * C * 2);
    float* a     = (float*)alloc((size_t)(EE + NN) * 4);
    float* alpha = (float*)alloc((size_t)(EE + NN) * 4);
    int* deg     = (int*)alloc((size_t)NN * 4);
    int* row_ptr = (int*)alloc((size_t)(NN + 1) * 4);
    int* fill    = (int*)alloc((size_t)NN * 4);
    int* eid     = (int*)alloc((size_t)EE * 4);
    float* sums  = (float*)alloc(2 * C * 4);
    int* gs      = (int*)alloc(GG * 4);
    int* ge      = (int*)alloc(GG * 4);
    float* pooled= (float*)alloc(GG * C * 4);

    hipMemsetAsync(deg,  0, (size_t)NN * 4, stream);
    hipMemsetAsync(fill, 0, (size_t)NN * 4, stream);
    hipMemsetAsync(gs,   0, GG * 4, stream);
    hipMemsetAsync(ge,   0, GG * 4, stream);

    k_count<<<(EE + 255) / 256, 256, 0, stream>>>(dst, deg);
    k_scan<<<1, 1024, 0, stream>>>(deg, row_ptr);
    k_fill<<<(EE + 255) / 256, 256, 0, stream>>>(dst, row_ptr, fill, eid);

    int gN = (NN + 127) / 128, gE = (EE + 127) / 128;
    long long tw = (long long)(EE + NN) * 64;
    int apassBlocks = (int)((tw + 255) / 256);

    // ---- layer 1 ----
    k_gemm_mfma<false, false><<<gN, 256, 0, stream>>>(x, Wl1, bl1, B0, NN);
    k_gemm_mfma<false, false><<<gN, 256, 0, stream>>>(x, Wr1, br1, B1, NN);
    k_gemm_mfma<false, true ><<<gE, 256, 0, stream>>>(ea, We1, nullptr, eW, EE);
    k_loopw<<<NN, C, 0, stream>>>(eW, row_ptr, eid, deg, B2);
    k_apass<<<apassBlocks, 256, 0, stream>>>(B0, B1, eW, B2, src, dst, att1, a);
    k_softmax<<<(NN + 255) / 256, 256, 0, stream>>>(row_ptr, eid, a, alpha);
    k_agg<<<NN, C, 0, stream>>>(B0, alpha, row_ptr, eid, src, bo1, B3);
    hipMemsetAsync(sums, 0, 2 * C * 4, stream);
    k_bnstats<<<256, C, 0, stream>>>(B3, sums);
    k_bnapply<<<(NN * C + 255) / 256, 256, 0, stream>>>(B3, sums, g1, be1, B0); // h -> B0

    // ---- layer 2 ----
    k_gemm_mfma<false, false><<<gN, 256, 0, stream>>>(B0, Wl2, bl2, B1, NN);
    k_gemm_mfma<false, false><<<gN, 256, 0, stream>>>(B0, Wr2, br2, B2, NN);
    k_gemm_mfma<false, true ><<<gE, 256, 0, stream>>>(ea, We2, nullptr, eW, EE);
    k_loopw<<<NN, C, 0, stream>>>(eW, row_ptr, eid, deg, B3);
    k_apass<<<apassBlocks, 256, 0, stream>>>(B1, B2, eW, B3, src, dst, att2, a);
    k_softmax<<<(NN + 255) / 256, 256, 0, stream>>>(row_ptr, eid, a, alpha);
    k_agg<<<NN, C, 0, stream>>>(B1, alpha, row_ptr, eid, src, bo2, B0);
    hipMemsetAsync(sums, 0, 2 * C * 4, stream);
    k_bnstats<<<256, C, 0, stream>>>(B0, sums);
    k_bnapply<<<(NN * C + 255) / 256, 256, 0, stream>>>(B0, sums, g2, be2, B3); // h2 -> B3

    // ---- pooling + head ----
    k_gemm_mfma<true,  false><<<gN, 256, 0, stream>>>(B3, Ag1, bg1, B1, NN);
    k_gemm_mfma<false, false><<<gN, 256, 0, stream>>>(B1, Ag2, bg2, B2, NN);
    k_bounds<<<(NN + 255) / 256, 256, 0, stream>>>(batch, gs, ge);
    k_pool<<<GG, C, 0, stream>>>(B2, B3, gs, ge, pooled);
    k_final<<<GG, C, 0, stream>>>(pooled, Wf, bf, (float*)d_out);
}

// Round 3
// 1730.706 us; speedup vs baseline: 3.9667x; 1.1684x over previous
//
#include <hip/hip_runtime.h>
#include <hip/hip_bf16.h>
#include <math.h>

#define C 128
#define NN 50000
#define EE 600000
#define GG 256
#define PI_F 3.14159265358979323846f
#define EPS_BN 1e-5f

typedef __attribute__((ext_vector_type(8)))  short  short8;
typedef __attribute__((ext_vector_type(16))) float  floatx16;
typedef __attribute__((ext_vector_type(4)))  float  float4v;

static __device__ __forceinline__ short f2bs(float x) {
    union { float f; unsigned u; } v; v.f = x;
    unsigned r = v.u + 0x7FFF + ((v.u >> 16) & 1);
    return (short)(r >> 16);
}

// ---------------- CSR build ----------------
__global__ void k_count(const int* __restrict__ dst, int* __restrict__ deg) {
    int e = blockIdx.x * blockDim.x + threadIdx.x;
    if (e < EE) atomicAdd(&deg[dst[e]], 1);
}

__global__ void k_scan(const int* __restrict__ deg, int* __restrict__ row_ptr) {
    __shared__ int s[1024];
    int t = threadIdx.x;
    const int CH = (NN + 1023) / 1024;
    int base = t * CH;
    int loc = 0;
    for (int i = 0; i < CH; i++) { int idx = base + i; if (idx < NN) loc += deg[idx]; }
    s[t] = loc; __syncthreads();
    for (int off = 1; off < 1024; off <<= 1) {
        int v = (t >= off) ? s[t - off] : 0;
        __syncthreads();
        s[t] += v;
        __syncthreads();
    }
    int run = (t == 0) ? 0 : s[t - 1];
    for (int i = 0; i < CH; i++) {
        int idx = base + i;
        if (idx < NN) { row_ptr[idx] = run; run += deg[idx]; }
    }
    if (t == 0) row_ptr[NN] = s[1023];
}

__global__ void k_fill(const int* __restrict__ dst, const int* __restrict__ row_ptr,
                       int* __restrict__ fill, int* __restrict__ eid) {
    int e = blockIdx.x * blockDim.x + threadIdx.x;
    if (e < EE) {
        int d = dst[e];
        int pos = atomicAdd(&fill[d], 1);
        eid[row_ptr[d] + pos] = e;
    }
}

// ---------------- esum[n] = segment_sum(ea, dst)[n] / max(deg,1) (layer-independent) ----
__global__ void k_esum(const float* __restrict__ ea, const int* __restrict__ row_ptr,
                       const int* __restrict__ eid, const int* __restrict__ deg,
                       float* __restrict__ esum) {
    int n = blockIdx.x; int c = threadIdx.x;
    int s = row_ptr[n], e = row_ptr[n + 1];
    float acc = 0.f;
    for (int i = s; i < e; i++) acc += ea[(size_t)eid[i] * C + c];
    esum[(size_t)n * C + c] = acc / fmaxf((float)deg[n], 1.f);
}

// ---------------- MFMA GEMM: out[M x C] = in[M x C] @ W[C x C] + b (f32 out) -------
template<bool TANH>
__launch_bounds__(256)
__global__ void k_gemm_mfma(const float* __restrict__ in, const float* __restrict__ W,
                            const float* __restrict__ bias, float* __restrict__ out, int M) {
    __shared__ short sWT[C * 136];
    for (int i = threadIdx.x; i < C * C; i += 256) {
        int k = i >> 7, n = i & (C - 1);
        sWT[n * 136 + k] = f2bs(W[i]);
    }
    __syncthreads();

    int lane = threadIdx.x & 63;
    int wave = threadIdx.x >> 6;
    int m    = lane & 31;
    int half = lane >> 5;
    int row0 = blockIdx.x * 128 + wave * 32;
    int rowA = row0 + m;
    int rowC = (rowA < M) ? rowA : (M - 1);
    const float* rp = in + (size_t)rowC * C;

    floatx16 acc[4];
    #pragma unroll
    for (int t = 0; t < 4; ++t)
        #pragma unroll
        for (int r = 0; r < 16; ++r) acc[t][r] = 0.f;

    #pragma unroll
    for (int s = 0; s < 8; ++s) {
        int k0 = s * 16 + half * 8;
        float4v a0 = *(const float4v*)(rp + k0);
        float4v a1 = *(const float4v*)(rp + k0 + 4);
        short8 af;
        af[0] = f2bs(a0.x); af[1] = f2bs(a0.y); af[2] = f2bs(a0.z); af[3] = f2bs(a0.w);
        af[4] = f2bs(a1.x); af[5] = f2bs(a1.y); af[6] = f2bs(a1.z); af[7] = f2bs(a1.w);
        #pragma unroll
        for (int t = 0; t < 4; ++t) {
            short8 bfr = *(const short8*)(&sWT[(t * 32 + m) * 136 + k0]);
            acc[t] = __builtin_amdgcn_mfma_f32_32x32x16_bf16(af, bfr, acc[t], 0, 0, 0);
        }
    }

    #pragma unroll
    for (int t = 0; t < 4; ++t) {
        int n = t * 32 + m;
        float b = bias ? bias[n] : 0.f;
        #pragma unroll
        for (int r = 0; r < 16; ++r) {
            int rl  = (r & 3) + 8 * (r >> 2) + 4 * half;
            int row = row0 + rl;
            if (row < M) {
                float v = acc[t][r] + b;
                if (TANH) v = tanhf(v);
                out[(size_t)row * C + n] = v;
            }
        }
    }
}

// ---------------- fused GEMM + attention logit ------------------------------------
// SELF=false: A=ea rows (edges), gather xl[src[e]], xr[dst[e]], write aout[e]
// SELF=true : A=esum rows (nodes), gather xl[n], xr[n],        write aout[n]
// aout = dot(leaky_relu(A@We + xl_g + xr_g, 0.2), att); eW never hits HBM.
template<bool SELF>
__launch_bounds__(256)
__global__ void k_gemm_logit(const float* __restrict__ A, const float* __restrict__ W,
                             const float* __restrict__ xl, const float* __restrict__ xr,
                             const int* __restrict__ src, const int* __restrict__ dst,
                             const float* __restrict__ att, float* __restrict__ aout, int M) {
    __shared__ short sWT[C * 136];
    for (int i = threadIdx.x; i < C * C; i += 256) {
        int k = i >> 7, n = i & (C - 1);
        sWT[n * 136 + k] = f2bs(W[i]);
    }
    __syncthreads();

    int lane = threadIdx.x & 63;
    int wave = threadIdx.x >> 6;
    int m    = lane & 31;
    int half = lane >> 5;
    int row0 = blockIdx.x * 128 + wave * 32;
    int rowA = row0 + m;
    int rowC = (rowA < M) ? rowA : (M - 1);
    const float* rp = A + (size_t)rowC * C;

    floatx16 acc[4];
    #pragma unroll
    for (int t = 0; t < 4; ++t)
        #pragma unroll
        for (int r = 0; r < 16; ++r) acc[t][r] = 0.f;

    #pragma unroll
    for (int s = 0; s < 8; ++s) {
        int k0 = s * 16 + half * 8;
        float4v a0 = *(const float4v*)(rp + k0);
        float4v a1 = *(const float4v*)(rp + k0 + 4);
        short8 af;
        af[0] = f2bs(a0.x); af[1] = f2bs(a0.y); af[2] = f2bs(a0.z); af[3] = f2bs(a0.w);
        af[4] = f2bs(a1.x); af[5] = f2bs(a1.y); af[6] = f2bs(a1.z); af[7] = f2bs(a1.w);
        #pragma unroll
        for (int t = 0; t < 4; ++t) {
            short8 bfr = *(const short8*)(&sWT[(t * 32 + m) * 136 + k0]);
            acc[t] = __builtin_amdgcn_mfma_f32_32x32x16_bf16(af, bfr, acc[t], 0, 0, 0);
        }
    }

    float attv[4];
    #pragma unroll
    for (int t = 0; t < 4; ++t) attv[t] = att[t * 32 + m];

    #pragma unroll
    for (int r = 0; r < 16; ++r) {
        int rl  = (r & 3) + 8 * (r >> 2) + 4 * half;
        int row = row0 + rl;
        int rc  = (row < M) ? row : (M - 1);
        int si, di;
        if (SELF) { si = rc; di = rc; }
        else      { si = src[rc]; di = dst[rc]; }
        const float* xls = xl + (size_t)si * C;
        const float* xrs = xr + (size_t)di * C;
        float p = 0.f;
        #pragma unroll
        for (int t = 0; t < 4; ++t) {
            int col = t * 32 + m;
            float v = acc[t][r] + xls[col] + xrs[col];
            v = (v >= 0.f) ? v : 0.2f * v;
            p = fmaf(v, attv[t], p);
        }
        p += __shfl_xor(p, 1);  p += __shfl_xor(p, 2);  p += __shfl_xor(p, 4);
        p += __shfl_xor(p, 8);  p += __shfl_xor(p, 16);
        if (m == 0 && row < M) aout[row] = p;
    }
}

// ---------------- scatter softmax (wave per node) ----------------
__global__ void k_softmax(const int* __restrict__ row_ptr, const int* __restrict__ eid,
                          const float* __restrict__ a, float* __restrict__ alpha) {
    int n = blockIdx.x * 4 + (threadIdx.x >> 6);
    int lane = threadIdx.x & 63;
    if (n >= NN) return;
    int s = row_ptr[n], e = row_ptr[n + 1];
    float self = a[EE + n];
    float mx = self;
    for (int i = s + lane; i < e; i += 64) mx = fmaxf(mx, a[eid[i]]);
    #pragma unroll
    for (int o = 1; o < 64; o <<= 1) mx = fmaxf(mx, __shfl_xor(mx, o));
    float exs = expf(self - mx);
    float den = (lane == 0) ? exs : 0.f;
    for (int i = s + lane; i < e; i += 64) {
        float ex = expf(a[eid[i]] - mx);
        alpha[eid[i]] = ex; den += ex;
    }
    #pragma unroll
    for (int o = 1; o < 64; o <<= 1) den += __shfl_xor(den, o);
    float inv = 1.f / den;
    for (int i = s + lane; i < e; i += 64) alpha[eid[i]] *= inv;
    if (lane == 0) alpha[EE + n] = exs * inv;
}

// ---------------- aggregation ----------------
__global__ void k_agg(const float* __restrict__ xl, const float* __restrict__ alpha,
                      const int* __restrict__ row_ptr, const int* __restrict__ eid,
                      const int* __restrict__ src, const float* __restrict__ bo,
                      float* __restrict__ out) {
    int n = blockIdx.x; int c = threadIdx.x;
    float acc = alpha[EE + n] * xl[(size_t)n * C + c];
    int s = row_ptr[n], e = row_ptr[n + 1];
    for (int i = s; i < e; i++) {
        int ed = eid[i];
        acc += alpha[ed] * xl[(size_t)src[ed] * C + c];
    }
    out[(size_t)n * C + c] = acc + bo[c];
}

// ---------------- batchnorm ----------------
__global__ void k_bnstats(const float* __restrict__ v, float* __restrict__ sums) {
    int c = threadIdx.x;
    float s1 = 0.f, s2 = 0.f;
    for (int n = blockIdx.x; n < NN; n += gridDim.x) {
        float x = v[(size_t)n * C + c]; s1 += x; s2 += x * x;
    }
    atomicAdd(&sums[c], s1); atomicAdd(&sums[C + c], s2);
}

__global__ void k_bnapply(const float* __restrict__ v, const float* __restrict__ sums,
                          const float* __restrict__ g, const float* __restrict__ b,
                          float* __restrict__ h) {
    int idx = blockIdx.x * blockDim.x + threadIdx.x;
    if (idx >= NN * C) return;
    int c = idx & (C - 1);
    float mu  = sums[c] * (1.f / NN);
    float var = sums[C + c] * (1.f / NN) - mu * mu;
    float r = rsqrtf(var + EPS_BN);
    h[idx] = tanhf((v[idx] - mu) * r * g[c] + b[c]);
}

// ---------------- graph segment bounds ----------------
__global__ void k_bounds(const int* __restrict__ batch, int* __restrict__ gs, int* __restrict__ ge) {
    int n = blockIdx.x * blockDim.x + threadIdx.x;
    if (n >= NN) return;
    int b = batch[n];
    if (n == 0 || batch[n - 1] != b) gs[b] = n;
    if (n == NN - 1 || batch[n + 1] != b) ge[b] = n + 1;
}

// ---------------- attention pooling (block per graph) ----------------
__global__ void k_pool(const float* __restrict__ gate, const float* __restrict__ h,
                       const int* __restrict__ gs, const int* __restrict__ ge,
                       float* __restrict__ pooled) {
    int g = blockIdx.x; int c = threadIdx.x;
    int s = gs[g], e = ge[g];
    float m = -1e30f;
    for (int n = s; n < e; n++) m = fmaxf(m, gate[(size_t)n * C + c]);
    float den = 0.f, acc = 0.f;
    for (int n = s; n < e; n++) {
        float w = expf(gate[(size_t)n * C + c] - m);
        den += w; acc += w * h[(size_t)n * C + c];
    }
    pooled[g * C + c] = (e > s) ? acc / den : 0.f;
}

// ---------------- final linear + tanh + split/scale ----------------
__global__ void k_final(const float* __restrict__ pooled, const float* __restrict__ Wf,
                        const float* __restrict__ bf, float* __restrict__ out) {
    __shared__ float row[C];
    int g = blockIdx.x; int j = threadIdx.x;
    row[j] = pooled[g * C + j];
    __syncthreads();
    float acc = bf[j];
    #pragma unroll 8
    for (int k = 0; k < C; k++) acc = fmaf(row[k], Wf[k * C + j], acc);
    float o = tanhf(acc);
    if (j < C / 2) out[g * (C / 2) + j] = o * PI_F;
    else out[GG * (C / 2) + g * (C / 2) + (j - C / 2)] = (o + 1.f) * PI_F;
}

extern "C" void kernel_launch(void* const* d_in, const int* in_sizes, int n_in,
                              void* d_out, int out_size, void* d_ws, size_t ws_size,
                              hipStream_t stream) {
    const float* x   = (const float*)d_in[0];
    const int*   ei  = (const int*)d_in[1];
    const float* ea  = (const float*)d_in[2];
    const int* batch = (const int*)d_in[3];
    const float *Wl1 = (const float*)d_in[4],  *bl1 = (const float*)d_in[5];
    const float *Wr1 = (const float*)d_in[6],  *br1 = (const float*)d_in[7];
    const float *We1 = (const float*)d_in[8],  *att1 = (const float*)d_in[9], *bo1 = (const float*)d_in[10];
    const float *Wl2 = (const float*)d_in[11], *bl2 = (const float*)d_in[12];
    const float *Wr2 = (const float*)d_in[13], *br2 = (const float*)d_in[14];
    const float *We2 = (const float*)d_in[15], *att2 = (const float*)d_in[16], *bo2 = (const float*)d_in[17];
    const float *g1  = (const float*)d_in[18], *be1 = (const float*)d_in[19];
    const float *g2  = (const float*)d_in[20], *be2 = (const float*)d_in[21];
    const float *Ag1 = (const float*)d_in[22], *bg1 = (const float*)d_in[23];
    const float *Ag2 = (const float*)d_in[24], *bg2 = (const float*)d_in[25];
    const float *Wf  = (const float*)d_in[26], *bf  = (const float*)d_in[27];
    const int* src = ei; const int* dst = ei + EE;

    char* wsb = (char*)d_ws;
    size_t off = 0;
    auto alloc = [&](size_t bytes) -> char* {
        char* p = wsb + off; off += (bytes + 255) & ~(size_t)255; return p;
    };
    float* B0   = (float*)alloc((size_t)NN * C * 4);   // xl
    float* B1   = (float*)alloc((size_t)NN * C * 4);   // xr / gate2
    float* B3   = (float*)alloc((size_t)NN * C * 4);   // agg out / h
    float* esum = (float*)alloc((size_t)NN * C * 4);   // persists both layers
    float* a     = (float*)alloc((size_t)(EE + NN) * 4);
    float* alpha = (float*)alloc((size_t)(EE + NN) * 4);
    int* deg     = (int*)alloc((size_t)NN * 4);
    int* row_ptr = (int*)alloc((size_t)(NN + 1) * 4);
    int* fill    = (int*)alloc((size_t)NN * 4);
    int* eid     = (int*)alloc((size_t)EE * 4);
    float* sums  = (float*)alloc(2 * C * 4);
    int* gs      = (int*)alloc(GG * 4);
    int* ge      = (int*)alloc(GG * 4);
    float* pooled= (float*)alloc(GG * C * 4);

    hipMemsetAsync(deg,  0, (size_t)NN * 4, stream);
    hipMemsetAsync(fill, 0, (size_t)NN * 4, stream);
    hipMemsetAsync(gs,   0, GG * 4, stream);
    hipMemsetAsync(ge,   0, GG * 4, stream);

    k_count<<<(EE + 255) / 256, 256, 0, stream>>>(dst, deg);
    k_scan<<<1, 1024, 0, stream>>>(deg, row_ptr);
    k_fill<<<(EE + 255) / 256, 256, 0, stream>>>(dst, row_ptr, fill, eid);
    k_esum<<<NN, C, 0, stream>>>(ea, row_ptr, eid, deg, esum);

    int gN = (NN + 127) / 128, gE = (EE + 127) / 128;

    // ---- layer 1 ----
    k_gemm_mfma<false><<<gN, 256, 0, stream>>>(x, Wl1, bl1, B0, NN);
    k_gemm_mfma<false><<<gN, 256, 0, stream>>>(x, Wr1, br1, B1, NN);
    k_gemm_logit<true ><<<gN, 256, 0, stream>>>(esum, We1, B0, B1, src, dst, att1, a + EE, NN);
    k_gemm_logit<false><<<gE, 256, 0, stream>>>(ea,   We1, B0, B1, src, dst, att1, a, EE);
    k_softmax<<<(NN + 3) / 4, 256, 0, stream>>>(row_ptr, eid, a, alpha);
    k_agg<<<NN, C, 0, stream>>>(B0, alpha, row_ptr, eid, src, bo1, B3);
    hipMemsetAsync(sums, 0, 2 * C * 4, stream);
    k_bnstats<<<256, C, 0, stream>>>(B3, sums);
    k_bnapply<<<(NN * C + 255) / 256, 256, 0, stream>>>(B3, sums, g1, be1, B3); // h1 in-place

    // ---- layer 2 ----
    k_gemm_mfma<false><<<gN, 256, 0, stream>>>(B3, Wl2, bl2, B0, NN);
    k_gemm_mfma<false><<<gN, 256, 0, stream>>>(B3, Wr2, br2, B1, NN);
    k_gemm_logit<true ><<<gN, 256, 0, stream>>>(esum, We2, B0, B1, src, dst, att2, a + EE, NN);
    k_gemm_logit<false><<<gE, 256, 0, stream>>>(ea,   We2, B0, B1, src, dst, att2, a, EE);
    k_softmax<<<(NN + 3) / 4, 256, 0, stream>>>(row_ptr, eid, a, alpha);
    k_agg<<<NN, C, 0, stream>>>(B0, alpha, row_ptr, eid, src, bo2, B3);
    hipMemsetAsync(sums, 0, 2 * C * 4, stream);
    k_bnstats<<<256, C, 0, stream>>>(B3, sums);
    k_bnapply<<<(NN * C + 255) / 256, 256, 0, stream>>>(B3, sums, g2, be2, B3); // h2 in-place

    // ---- pooling + head ----
    k_gemm_mfma<true ><<<gN, 256, 0, stream>>>(B3, Ag1, bg1, B0, NN);
    k_gemm_mfma<false><<<gN, 256, 0, stream>>>(B0, Ag2, bg2, B1, NN);
    k_bounds<<<(NN + 255) / 256, 256, 0, stream>>>(batch, gs, ge);
    k_pool<<<GG, C, 0, stream>>>(B1, B3, gs, ge, pooled);
    k_final<<<GG, C, 0, stream>>>(pooled, Wf, bf, (float*)d_out);
}

// Round 4
// 1537.268 us; speedup vs baseline: 4.4658x; 1.1258x over previous
//
#include <hip/hip_runtime.h>
#include <hip/hip_bf16.h>
#include <math.h>

#define C 128
#define NN 50000
#define EE 600000
#define GG 256
#define PI_F 3.14159265358979323846f
#define EPS_BN 1e-5f

typedef __attribute__((ext_vector_type(8)))  short  short8;
typedef __attribute__((ext_vector_type(16))) float  floatx16;
typedef __attribute__((ext_vector_type(4)))  float  float4v;
typedef __attribute__((ext_vector_type(4)))  unsigned short ushort4v;

static __device__ __forceinline__ short f2bs(float x) {   // f32 -> bf16 bits (RNE)
    union { float f; unsigned u; } v; v.f = x;
    unsigned r = v.u + 0x7FFF + ((v.u >> 16) & 1);
    return (short)(r >> 16);
}
static __device__ __forceinline__ float bs2f(unsigned short b) {
    union { unsigned u; float f; } v; v.u = (unsigned)b << 16; return v.f;
}

// ---------------- f32 -> bf16 cast (vectorized) ----------------
__global__ void k_cast(const float* __restrict__ in, unsigned short* __restrict__ out, int n4) {
    int i = blockIdx.x * blockDim.x + threadIdx.x;
    if (i < n4) {
        float4v v = ((const float4v*)in)[i];
        ushort4v o;
        o.x = (unsigned short)f2bs(v.x); o.y = (unsigned short)f2bs(v.y);
        o.z = (unsigned short)f2bs(v.z); o.w = (unsigned short)f2bs(v.w);
        ((ushort4v*)out)[i] = o;
    }
}

// ---------------- CSR build ----------------
__global__ void k_count(const int* __restrict__ dst, int* __restrict__ deg) {
    int e = blockIdx.x * blockDim.x + threadIdx.x;
    if (e < EE) atomicAdd(&deg[dst[e]], 1);
}

__global__ void k_scan(const int* __restrict__ deg, int* __restrict__ row_ptr) {
    __shared__ int s[1024];
    int t = threadIdx.x;
    const int CH = (NN + 1023) / 1024;
    int base = t * CH;
    int loc = 0;
    for (int i = 0; i < CH; i++) { int idx = base + i; if (idx < NN) loc += deg[idx]; }
    s[t] = loc; __syncthreads();
    for (int off = 1; off < 1024; off <<= 1) {
        int v = (t >= off) ? s[t - off] : 0;
        __syncthreads();
        s[t] += v;
        __syncthreads();
    }
    int run = (t == 0) ? 0 : s[t - 1];
    for (int i = 0; i < CH; i++) {
        int idx = base + i;
        if (idx < NN) { row_ptr[idx] = run; run += deg[idx]; }
    }
    if (t == 0) row_ptr[NN] = s[1023];
}

__global__ void k_fill(const int* __restrict__ dst, const int* __restrict__ row_ptr,
                       int* __restrict__ fill, int* __restrict__ eid) {
    int e = blockIdx.x * blockDim.x + threadIdx.x;
    if (e < EE) {
        int d = dst[e];
        int pos = atomicAdd(&fill[d], 1);
        eid[row_ptr[d] + pos] = e;
    }
}

// ---------------- esum[n] = segment_sum(ea, dst)[n] / max(deg,1), bf16 in/out ----
__global__ void k_esum(const unsigned short* __restrict__ ea, const int* __restrict__ row_ptr,
                       const int* __restrict__ eid, const int* __restrict__ deg,
                       unsigned short* __restrict__ esum) {
    int n = blockIdx.x; int c = threadIdx.x;
    int s = row_ptr[n], e = row_ptr[n + 1];
    float acc = 0.f;
    for (int i = s; i < e; i++) acc += bs2f(ea[(size_t)eid[i] * C + c]);
    esum[(size_t)n * C + c] = (unsigned short)f2bs(acc / fmaxf((float)deg[n], 1.f));
}

// ---------------- MFMA GEMM (bf16 A): out = A @ W + b ----------------
template<bool TANH, bool OUT_BF16>
__launch_bounds__(256)
__global__ void k_gemm(const unsigned short* __restrict__ A, const float* __restrict__ W,
                       const float* __restrict__ bias, void* __restrict__ outv, int M) {
    __shared__ short sWT[C * 136];
    for (int i = threadIdx.x; i < C * C; i += 256) {
        int k = i >> 7, n = i & (C - 1);
        sWT[n * 136 + k] = f2bs(W[i]);
    }
    __syncthreads();

    int lane = threadIdx.x & 63;
    int wave = threadIdx.x >> 6;
    int m    = lane & 31;
    int half = lane >> 5;
    int row0 = blockIdx.x * 128 + wave * 32;
    int rowA = row0 + m;
    int rowC = (rowA < M) ? rowA : (M - 1);
    const unsigned short* rp = A + (size_t)rowC * C;

    floatx16 acc[4];
    #pragma unroll
    for (int t = 0; t < 4; ++t)
        #pragma unroll
        for (int r = 0; r < 16; ++r) acc[t][r] = 0.f;

    #pragma unroll
    for (int s = 0; s < 8; ++s) {
        int k0 = s * 16 + half * 8;
        short8 af = *(const short8*)(rp + k0);
        #pragma unroll
        for (int t = 0; t < 4; ++t) {
            short8 bfr = *(const short8*)(&sWT[(t * 32 + m) * 136 + k0]);
            acc[t] = __builtin_amdgcn_mfma_f32_32x32x16_bf16(af, bfr, acc[t], 0, 0, 0);
        }
    }

    #pragma unroll
    for (int t = 0; t < 4; ++t) {
        int n = t * 32 + m;
        float b = bias ? bias[n] : 0.f;
        #pragma unroll
        for (int r = 0; r < 16; ++r) {
            int rl  = (r & 3) + 8 * (r >> 2) + 4 * half;
            int row = row0 + rl;
            if (row < M) {
                float v = acc[t][r] + b;
                if (TANH) v = tanhf(v);
                if (OUT_BF16) ((unsigned short*)outv)[(size_t)row * C + n] = (unsigned short)f2bs(v);
                else          ((float*)outv)[(size_t)row * C + n] = v;
            }
        }
    }
}

// ---------------- dual GEMM: xl = A@W0+b0, xr = A@W1+b1 (A frags cached) --------
__launch_bounds__(256)
__global__ void k_gemm2(const unsigned short* __restrict__ A,
                        const float* __restrict__ W0, const float* __restrict__ b0,
                        const float* __restrict__ W1, const float* __restrict__ b1,
                        unsigned short* __restrict__ out0, unsigned short* __restrict__ out1,
                        int M) {
    __shared__ short sWT[C * 136];
    int lane = threadIdx.x & 63;
    int wave = threadIdx.x >> 6;
    int m    = lane & 31;
    int half = lane >> 5;
    int row0 = blockIdx.x * 128 + wave * 32;
    int rowA = row0 + m;
    int rowC = (rowA < M) ? rowA : (M - 1);
    const unsigned short* rp = A + (size_t)rowC * C;

    short8 af[8];
    #pragma unroll
    for (int s = 0; s < 8; ++s) af[s] = *(const short8*)(rp + s * 16 + half * 8);

    for (int phase = 0; phase < 2; ++phase) {
        const float* W = phase ? W1 : W0;
        const float* bb = phase ? b1 : b0;
        unsigned short* out = phase ? out1 : out0;
        if (phase) __syncthreads();   // all waves done reading previous sWT
        for (int i = threadIdx.x; i < C * C; i += 256) {
            int k = i >> 7, n = i & (C - 1);
            sWT[n * 136 + k] = f2bs(W[i]);
        }
        __syncthreads();

        floatx16 acc[4];
        #pragma unroll
        for (int t = 0; t < 4; ++t)
            #pragma unroll
            for (int r = 0; r < 16; ++r) acc[t][r] = 0.f;

        #pragma unroll
        for (int s = 0; s < 8; ++s) {
            int k0 = s * 16 + half * 8;
            #pragma unroll
            for (int t = 0; t < 4; ++t) {
                short8 bfr = *(const short8*)(&sWT[(t * 32 + m) * 136 + k0]);
                acc[t] = __builtin_amdgcn_mfma_f32_32x32x16_bf16(af[s], bfr, acc[t], 0, 0, 0);
            }
        }

        #pragma unroll
        for (int t = 0; t < 4; ++t) {
            int n = t * 32 + m;
            float b = bb[n];
            #pragma unroll
            for (int r = 0; r < 16; ++r) {
                int rl  = (r & 3) + 8 * (r >> 2) + 4 * half;
                int row = row0 + rl;
                if (row < M)
                    out[(size_t)row * C + n] = (unsigned short)f2bs(acc[t][r] + b);
            }
        }
    }
}

// ---------------- fused GEMM + attention logit (bf16 A, bf16 gathers) -----------
template<bool SELF>
__launch_bounds__(256)
__global__ void k_gemm_logit(const unsigned short* __restrict__ A, const float* __restrict__ W,
                             const unsigned short* __restrict__ xl, const unsigned short* __restrict__ xr,
                             const int* __restrict__ src, const int* __restrict__ dst,
                             const float* __restrict__ att, float* __restrict__ aout, int M) {
    __shared__ short sWT[C * 136];
    for (int i = threadIdx.x; i < C * C; i += 256) {
        int k = i >> 7, n = i & (C - 1);
        sWT[n * 136 + k] = f2bs(W[i]);
    }
    __syncthreads();

    int lane = threadIdx.x & 63;
    int wave = threadIdx.x >> 6;
    int m    = lane & 31;
    int half = lane >> 5;
    int row0 = blockIdx.x * 128 + wave * 32;
    int rowA = row0 + m;
    int rowC = (rowA < M) ? rowA : (M - 1);
    const unsigned short* rp = A + (size_t)rowC * C;

    floatx16 acc[4];
    #pragma unroll
    for (int t = 0; t < 4; ++t)
        #pragma unroll
        for (int r = 0; r < 16; ++r) acc[t][r] = 0.f;

    #pragma unroll
    for (int s = 0; s < 8; ++s) {
        int k0 = s * 16 + half * 8;
        short8 af = *(const short8*)(rp + k0);
        #pragma unroll
        for (int t = 0; t < 4; ++t) {
            short8 bfr = *(const short8*)(&sWT[(t * 32 + m) * 136 + k0]);
            acc[t] = __builtin_amdgcn_mfma_f32_32x32x16_bf16(af, bfr, acc[t], 0, 0, 0);
        }
    }

    float attv[4];
    #pragma unroll
    for (int t = 0; t < 4; ++t) attv[t] = att[t * 32 + m];

    #pragma unroll
    for (int r = 0; r < 16; ++r) {
        int rl  = (r & 3) + 8 * (r >> 2) + 4 * half;
        int row = row0 + rl;
        int rc  = (row < M) ? row : (M - 1);
        int si, di;
        if (SELF) { si = rc; di = rc; }
        else      { si = src[rc]; di = dst[rc]; }
        const unsigned short* xls = xl + (size_t)si * C;
        const unsigned short* xrs = xr + (size_t)di * C;
        float p = 0.f;
        #pragma unroll
        for (int t = 0; t < 4; ++t) {
            int col = t * 32 + m;
            float v = acc[t][r] + bs2f(xls[col]) + bs2f(xrs[col]);
            v = (v >= 0.f) ? v : 0.2f * v;
            p = fmaf(v, attv[t], p);
        }
        p += __shfl_xor(p, 1);  p += __shfl_xor(p, 2);  p += __shfl_xor(p, 4);
        p += __shfl_xor(p, 8);  p += __shfl_xor(p, 16);
        if (m == 0 && row < M) aout[row] = p;
    }
}

// ---------------- fused scatter-softmax + aggregation (wave per node) -----------
__global__ void k_attn(const unsigned short* __restrict__ xl, const float* __restrict__ a,
                       const int* __restrict__ row_ptr, const int* __restrict__ eid,
                       const int* __restrict__ src, const float* __restrict__ bo,
                       float* __restrict__ out) {
    int n = blockIdx.x * 4 + (threadIdx.x >> 6);
    int lane = threadIdx.x & 63;
    if (n >= NN) return;
    int s = row_ptr[n], e = row_ptr[n + 1];
    float aself = a[EE + n];
    float mx = aself;
    for (int i = s + lane; i < e; i += 64) mx = fmaxf(mx, a[eid[i]]);
    #pragma unroll
    for (int o = 1; o < 64; o <<= 1) mx = fmaxf(mx, __shfl_xor(mx, o));
    float part = (lane == 0) ? expf(aself - mx) : 0.f;
    for (int i = s + lane; i < e; i += 64) part += expf(a[eid[i]] - mx);
    #pragma unroll
    for (int o = 1; o < 64; o <<= 1) part += __shfl_xor(part, o);
    float inv = 1.f / part;

    int c0 = lane * 2;
    float wself = expf(aself - mx) * inv;
    unsigned v = *(const unsigned*)(xl + (size_t)n * C + c0);
    union { unsigned u; float f; } lo, hi;
    lo.u = v << 16; hi.u = v & 0xFFFF0000u;
    float acc0 = wself * lo.f, acc1 = wself * hi.f;

    // serial over incoming edges, 1-deep prefetch on eid->a/src chain
    int i = s;
    int ed = 0, sd = 0; float av = 0.f;
    if (i < e) { ed = eid[i]; av = a[ed]; sd = src[ed]; }
    while (i < e) {
        int ed_n = 0, sd_n = 0; float av_n = 0.f;
        if (i + 1 < e) { ed_n = eid[i + 1]; av_n = a[ed_n]; sd_n = src[ed_n]; }
        float w = expf(av - mx) * inv;
        unsigned vv = *(const unsigned*)(xl + (size_t)sd * C + c0);
        union { unsigned u; float f; } l2, h2;
        l2.u = vv << 16; h2.u = vv & 0xFFFF0000u;
        acc0 = fmaf(w, l2.f, acc0);
        acc1 = fmaf(w, h2.f, acc1);
        ed = ed_n; av = av_n; sd = sd_n; ++i;
    }
    out[(size_t)n * C + c0]     = acc0 + bo[c0];
    out[(size_t)n * C + c0 + 1] = acc1 + bo[c0 + 1];
}

// ---------------- batchnorm ----------------
__global__ void k_bnstats(const float* __restrict__ v, float* __restrict__ sums) {
    int c = threadIdx.x;
    float s1 = 0.f, s2 = 0.f;
    for (int n = blockIdx.x; n < NN; n += gridDim.x) {
        float x = v[(size_t)n * C + c]; s1 += x; s2 += x * x;
    }
    atomicAdd(&sums[c], s1); atomicAdd(&sums[C + c], s2);
}

__global__ void k_bnapply(const float* __restrict__ v, const float* __restrict__ sums,
                          const float* __restrict__ g, const float* __restrict__ b,
                          unsigned short* __restrict__ h) {
    int idx = blockIdx.x * blockDim.x + threadIdx.x;
    if (idx >= NN * C) return;
    int c = idx & (C - 1);
    float mu  = sums[c] * (1.f / NN);
    float var = sums[C + c] * (1.f / NN) - mu * mu;
    float r = rsqrtf(var + EPS_BN);
    h[idx] = (unsigned short)f2bs(tanhf((v[idx] - mu) * r * g[c] + b[c]));
}

// ---------------- graph segment bounds ----------------
__global__ void k_bounds(const int* __restrict__ batch, int* __restrict__ gs, int* __restrict__ ge) {
    int n = blockIdx.x * blockDim.x + threadIdx.x;
    if (n >= NN) return;
    int b = batch[n];
    if (n == 0 || batch[n - 1] != b) gs[b] = n;
    if (n == NN - 1 || batch[n + 1] != b) ge[b] = n + 1;
}

// ---------------- attention pooling (block per graph, bf16 gate/h) --------------
__global__ void k_pool(const unsigned short* __restrict__ gate, const unsigned short* __restrict__ h,
                       const int* __restrict__ gs, const int* __restrict__ ge,
                       float* __restrict__ pooled) {
    int g = blockIdx.x; int c = threadIdx.x;
    int s = gs[g], e = ge[g];
    float m = -1e30f;
    for (int n = s; n < e; n++) m = fmaxf(m, bs2f(gate[(size_t)n * C + c]));
    float den = 0.f, acc = 0.f;
    for (int n = s; n < e; n++) {
        float w = expf(bs2f(gate[(size_t)n * C + c]) - m);
        den += w; acc += w * bs2f(h[(size_t)n * C + c]);
    }
    pooled[g * C + c] = (e > s) ? acc / den : 0.f;
}

// ---------------- final linear + tanh + split/scale ----------------
__global__ void k_final(const float* __restrict__ pooled, const float* __restrict__ Wf,
                        const float* __restrict__ bf, float* __restrict__ out) {
    __shared__ float row[C];
    int g = blockIdx.x; int j = threadIdx.x;
    row[j] = pooled[g * C + j];
    __syncthreads();
    float acc = bf[j];
    #pragma unroll 8
    for (int k = 0; k < C; k++) acc = fmaf(row[k], Wf[k * C + j], acc);
    float o = tanhf(acc);
    if (j < C / 2) out[g * (C / 2) + j] = o * PI_F;
    else out[GG * (C / 2) + g * (C / 2) + (j - C / 2)] = (o + 1.f) * PI_F;
}

extern "C" void kernel_launch(void* const* d_in, const int* in_sizes, int n_in,
                              void* d_out, int out_size, void* d_ws, size_t ws_size,
                              hipStream_t stream) {
    const float* x   = (const float*)d_in[0];
    const int*   ei  = (const int*)d_in[1];
    const float* ea  = (const float*)d_in[2];
    const int* batch = (const int*)d_in[3];
    const float *Wl1 = (const float*)d_in[4],  *bl1 = (const float*)d_in[5];
    const float *Wr1 = (const float*)d_in[6],  *br1 = (const float*)d_in[7];
    const float *We1 = (const float*)d_in[8],  *att1 = (const float*)d_in[9], *bo1 = (const float*)d_in[10];
    const float *Wl2 = (const float*)d_in[11], *bl2 = (const float*)d_in[12];
    const float *Wr2 = (const float*)d_in[13], *br2 = (const float*)d_in[14];
    const float *We2 = (const float*)d_in[15], *att2 = (const float*)d_in[16], *bo2 = (const float*)d_in[17];
    const float *g1  = (const float*)d_in[18], *be1 = (const float*)d_in[19];
    const float *g2  = (const float*)d_in[20], *be2 = (const float*)d_in[21];
    const float *Ag1 = (const float*)d_in[22], *bg1 = (const float*)d_in[23];
    const float *Ag2 = (const float*)d_in[24], *bg2 = (const float*)d_in[25];
    const float *Wf  = (const float*)d_in[26], *bf  = (const float*)d_in[27];
    const int* src = ei; const int* dst = ei + EE;

    char* wsb = (char*)d_ws;
    size_t off = 0;
    auto alloc = [&](size_t bytes) -> char* {
        char* p = wsb + off; off += (bytes + 255) & ~(size_t)255; return p;
    };
    unsigned short* ea_u  = (unsigned short*)alloc((size_t)EE * C * 2);
    unsigned short* x_u   = (unsigned short*)alloc((size_t)NN * C * 2);
    unsigned short* xl_u  = (unsigned short*)alloc((size_t)NN * C * 2);
    unsigned short* xr_u  = (unsigned short*)alloc((size_t)NN * C * 2);
    unsigned short* h_u   = (unsigned short*)alloc((size_t)NN * C * 2);
    unsigned short* es_u  = (unsigned short*)alloc((size_t)NN * C * 2);
    float* aggf  = (float*)alloc((size_t)NN * C * 4);
    float* a     = (float*)alloc((size_t)(EE + NN) * 4);
    int*   csrz  = (int*)alloc((size_t)2 * NN * 4);   // deg | fill (zeroed together)
    int* deg = csrz, *fill = csrz + NN;
    int* row_ptr = (int*)alloc((size_t)(NN + 1) * 4);
    int* eid     = (int*)alloc((size_t)EE * 4);
    float* sums  = (float*)alloc(4 * C * 4);          // layer1 | layer2
    int* gbounds = (int*)alloc(2 * GG * 4);
    int* gs = gbounds, *ge = gbounds + GG;
    float* pooled= (float*)alloc(GG * C * 4);

    hipMemsetAsync(csrz,    0, (size_t)2 * NN * 4, stream);
    hipMemsetAsync(sums,    0, 4 * C * 4, stream);
    hipMemsetAsync(gbounds, 0, 2 * GG * 4, stream);

    k_cast<<<(EE * C / 4 + 255) / 256, 256, 0, stream>>>(ea, ea_u, EE * C / 4);
    k_cast<<<(NN * C / 4 + 255) / 256, 256, 0, stream>>>(x,  x_u,  NN * C / 4);
    k_count<<<(EE + 255) / 256, 256, 0, stream>>>(dst, deg);
    k_scan<<<1, 1024, 0, stream>>>(deg, row_ptr);
    k_fill<<<(EE + 255) / 256, 256, 0, stream>>>(dst, row_ptr, fill, eid);
    k_esum<<<NN, C, 0, stream>>>(ea_u, row_ptr, eid, deg, es_u);

    int gN = (NN + 127) / 128, gE = (EE + 127) / 128;

    // ---- layer 1 ----
    k_gemm2<<<gN, 256, 0, stream>>>(x_u, Wl1, bl1, Wr1, br1, xl_u, xr_u, NN);
    k_gemm_logit<true ><<<gN, 256, 0, stream>>>(es_u, We1, xl_u, xr_u, src, dst, att1, a + EE, NN);
    k_gemm_logit<false><<<gE, 256, 0, stream>>>(ea_u, We1, xl_u, xr_u, src, dst, att1, a, EE);
    k_attn<<<(NN + 3) / 4, 256, 0, stream>>>(xl_u, a, row_ptr, eid, src, bo1, aggf);
    k_bnstats<<<256, C, 0, stream>>>(aggf, sums);
    k_bnapply<<<(NN * C + 255) / 256, 256, 0, stream>>>(aggf, sums, g1, be1, h_u);

    // ---- layer 2 ----
    k_gemm2<<<gN, 256, 0, stream>>>(h_u, Wl2, bl2, Wr2, br2, xl_u, xr_u, NN);
    k_gemm_logit<true ><<<gN, 256, 0, stream>>>(es_u, We2, xl_u, xr_u, src, dst, att2, a + EE, NN);
    k_gemm_logit<false><<<gE, 256, 0, stream>>>(ea_u, We2, xl_u, xr_u, src, dst, att2, a, EE);
    k_attn<<<(NN + 3) / 4, 256, 0, stream>>>(xl_u, a, row_ptr, eid, src, bo2, aggf);
    k_bnstats<<<256, C, 0, stream>>>(aggf, sums + 2 * C);
    k_bnapply<<<(NN * C + 255) / 256, 256, 0, stream>>>(aggf, sums + 2 * C, g2, be2, h_u);

    // ---- pooling + head ----
    k_gemm<true,  true><<<gN, 256, 0, stream>>>(h_u,  Ag1, bg1, xl_u, NN);
    k_gemm<false, true><<<gN, 256, 0, stream>>>(xl_u, Ag2, bg2, xr_u, NN);
    k_bounds<<<(NN + 255) / 256, 256, 0, stream>>>(batch, gs, ge);
    k_pool<<<GG, C, 0, stream>>>(xr_u, h_u, gs, ge, pooled);
    k_final<<<GG, C, 0, stream>>>(pooled, Wf, bf, (float*)d_out);
}